// Round 9
// baseline (280.203 us; speedup 1.0000x reference)
//
#include <hip/hip_runtime.h>

#define IN_SIZE 256
#define OUT_SIZE 64
#define BSHIFT 7         // 128-row buckets
#define BROWS 128
#define BMASK 127
#define CAP 2560         // bucket capacity: mean 2046, sigma 45 -> +11 sigma
#define K1_TILE 4096     // edges per K1 block (16 per thread)

typedef __attribute__((ext_vector_type(8))) short short8;   // 8 bf16, 4 VGPRs
typedef __attribute__((ext_vector_type(4))) float floatx4;  // MFMA acc

__device__ inline unsigned short f2bf(float f) {
  unsigned u = __builtin_bit_cast(unsigned, f);
  u += 0x7fff + ((u >> 16) & 1);  // round-to-nearest-even
  return (unsigned short)(u >> 16);
}
__device__ inline float bf2f(unsigned short u) {
  unsigned v = (unsigned)u << 16;
  return __builtin_bit_cast(float, v);
}

// ---------------------------------------------------------------------------
// Stage 0: W fp32 -> bf16 once + zero the coarse cursors (fused memset).
__global__ __launch_bounds__(256) void wconv_kernel(const float* __restrict__ W,
                                                    unsigned short* __restrict__ Wb,
                                                    int* __restrict__ coarse_cursor,
                                                    int total, int nbuck) {
  int i = blockIdx.x * 256 + threadIdx.x;
  if (i < total) Wb[i] = f2bf(W[i]);
  if (i < nbuck) coarse_cursor[i] = 0;
}

// ---------------------------------------------------------------------------
// K1: coarse bucketing by row>>7 into 782 padded regions.
// LDS hist -> one global atomicAdd per (block,bucket) -> scatter packed
// ((row&127)<<17 | col) via LDS-cursor ranks.
__global__ __launch_bounds__(256) void bucket_coarse_kernel(
    const int* __restrict__ row, const int* __restrict__ col,
    int* __restrict__ coarse_cursor, unsigned* __restrict__ pairs,
    int n_edges, int nbuck) {
  __shared__ int hist[1024];   // >= nbuck (782)
  int tid = threadIdx.x;
#pragma unroll
  for (int i = 0; i < 4; i++) hist[tid + i * 256] = 0;
  __syncthreads();

  int r[16], c[16];
  int ebase = blockIdx.x * K1_TILE + tid;
#pragma unroll
  for (int i = 0; i < 16; i++) {
    int e = ebase + i * 256;
    bool ok = e < n_edges;
    r[i] = ok ? row[e] : -1;
    c[i] = ok ? col[e] : -1;
    if (ok && r[i] != c[i]) atomicAdd(&hist[r[i] >> BSHIFT], 1);
  }
  __syncthreads();

  for (int i = tid; i < nbuck; i += 256) {
    int cnt = hist[i];
    if (cnt) hist[i] = atomicAdd(&coarse_cursor[i], cnt);
  }
  __syncthreads();

#pragma unroll
  for (int i = 0; i < 16; i++) {
    if (r[i] >= 0 && r[i] != c[i]) {
      int bin = r[i] >> BSHIFT;
      int slot = atomicAdd(&hist[bin], 1);  // LDS cursor
      if (slot < CAP)
        pairs[(size_t)bin * CAP + slot] =
            ((unsigned)(r[i] & BMASK) << 17) | (unsigned)c[i];
    }
  }
}

// ---------------------------------------------------------------------------
// K2: fine CSR build, single-pass. Bucket's pairs copied to LDS while
// histogramming (one global read of pairs total); scan + scatter consume
// the LDS copy. Rows disjoint per block -> plain stores for count/row_start/
// dinv.
__global__ __launch_bounds__(256) void bucket_fine_kernel(
    const int* __restrict__ coarse_cursor, const unsigned* __restrict__ pairs,
    unsigned* __restrict__ colsp, int* __restrict__ count,
    int* __restrict__ row_start, float* __restrict__ dinv, int n_nodes) {
  __shared__ unsigned lpair[CAP];  // 10 KB
  __shared__ int hist[BROWS];
  __shared__ int scn[BROWS];
  int tid = threadIdx.x;
  int b = blockIdx.x;
  size_t base = (size_t)b * CAP;
  int n_b = coarse_cursor[b];
  if (n_b > CAP) n_b = CAP;

  if (tid < BROWS) hist[tid] = 0;
  __syncthreads();

  for (int i = tid; i < n_b; i += 256) {  // copy + histogram in one pass
    unsigned p = pairs[base + i];
    lpair[i] = p;
    atomicAdd(&hist[p >> 17], 1);
  }
  __syncthreads();

  if (tid < BROWS) scn[tid] = hist[tid];
  __syncthreads();
  for (int off = 1; off < BROWS; off <<= 1) {
    int t = (tid >= off && tid < BROWS) ? scn[tid - off] : 0;
    __syncthreads();
    if (tid < BROWS) scn[tid] += t;
    __syncthreads();
  }

  if (tid < BROWS) {
    int e = (tid > 0) ? scn[tid - 1] : 0;
    int r = b * BROWS + tid;
    if (r < n_nodes) {
      int deg = hist[tid];
      count[r] = deg;
      row_start[r] = (int)base + e;
      dinv[r] = rsqrtf((float)deg + 1.0f);
    }
    hist[tid] = e;  // becomes scatter cursor
  }
  __syncthreads();

  for (int i = tid; i < n_b; i += 256) {
    unsigned p = lpair[i];
    int slot = atomicAdd(&hist[p >> 17], 1);
    colsp[base + slot] = p & 0x1FFFFu;
  }
}

// ---------------------------------------------------------------------------
// Stage 4: xwd = dinv * (x @ W.T), output bf16 [N][64]. 512 threads = 8 waves
// = 128 nodes per block: W staged to LDS once per 128 nodes (halved staging
// overhead vs 64-node blocks). Direct global->reg x loads; no barriers in
// the k-loop.
#define WPAD 264  // 256+8 shorts
__global__ __launch_bounds__(512) void matmul_kernel(
    const float* __restrict__ x, const unsigned short* __restrict__ Wb,
    const float* __restrict__ dinv, unsigned short* __restrict__ xwd,
    int n_nodes) {
  __shared__ unsigned short w_lds[64][WPAD];

  int tid = threadIdx.x;
  int wave = tid >> 6;    // 0..7
  int lane = tid & 63;
  int quad = lane >> 4;   // 0..3
  int lcol = lane & 15;   // 0..15
  long nbase = (long)blockIdx.x * 128;

  {  // stage W: 512 threads, each 32 shorts (4 x short8)
    int r = tid >> 3;     // 0..63
    int q = tid & 7;      // 8 chunks of 32 shorts
    const unsigned short* src = Wb + (size_t)r * IN_SIZE + q * 32;
#pragma unroll
    for (int i = 0; i < 4; i++)
      *(short8*)(&w_lds[r][q * 32 + i * 8]) = *(const short8*)(src + i * 8);
  }
  __syncthreads();

  long node = nbase + wave * 16 + lcol;
  long nclamp = (node < (long)n_nodes) ? node : (long)(n_nodes - 1);
  const float* xrow = x + nclamp * IN_SIZE;

  floatx4 acc[4];
#pragma unroll
  for (int t = 0; t < 4; t++) acc[t] = (floatx4){0.f, 0.f, 0.f, 0.f};

#pragma unroll
  for (int kk = 0; kk < 8; kk++) {
    const float* p = xrow + kk * 32 + quad * 8;
    float4 a = *(const float4*)(p);
    float4 bb = *(const float4*)(p + 4);
    short8 bfrag;
    bfrag[0] = (short)f2bf(a.x);  bfrag[1] = (short)f2bf(a.y);
    bfrag[2] = (short)f2bf(a.z);  bfrag[3] = (short)f2bf(a.w);
    bfrag[4] = (short)f2bf(bb.x); bfrag[5] = (short)f2bf(bb.y);
    bfrag[6] = (short)f2bf(bb.z); bfrag[7] = (short)f2bf(bb.w);
#pragma unroll
    for (int t = 0; t < 4; t++) {
      short8 afrag = *(const short8*)(&w_lds[t * 16 + lcol][kk * 32 + quad * 8]);
      acc[t] =
          __builtin_amdgcn_mfma_f32_16x16x32_bf16(afrag, bfrag, acc[t], 0, 0, 0);
    }
  }

  if (node < (long)n_nodes) {
    float dv = dinv[node];
#pragma unroll
    for (int t = 0; t < 4; t++) {
      ushort4 sv;
      sv.x = f2bf(dv * acc[t][0]);
      sv.y = f2bf(dv * acc[t][1]);
      sv.z = f2bf(dv * acc[t][2]);
      sv.w = f2bf(dv * acc[t][3]);
      *(ushort4*)(xwd + node * OUT_SIZE + t * 16 + quad * 4) = sv;
    }
  }
}

// ---------------------------------------------------------------------------
// Stage 5: CSR gather, 8 rows per wave (32 per block). lane = cg(0..7 channel
// group of 8) x sub(0..7 edge slot). Per strip the wave issues 8 colsp +
// 8 x 1KB xwd loads (64 edges in flight); register accumulate; one butterfly
// (xor 1,2,4) at the end. E[max deg of 8 rows] ~ 22 -> ~3 strips, same as the
// 4-row version but 2x rows per strip.
__global__ __launch_bounds__(256) void gather_kernel(
    const int* __restrict__ row_start, const int* __restrict__ count,
    const unsigned* __restrict__ colsp, const float* __restrict__ dinv,
    const unsigned short* __restrict__ xwd, float* __restrict__ out,
    int n_nodes) {
  int lane = threadIdx.x & 63;
  int wave = threadIdx.x >> 6;
  int sub = lane & 7;   // edge slot
  int cg = lane >> 3;   // channels cg*8 .. cg*8+7
  int rb = (blockIdx.x * 4 + wave) * 8;  // first of 8 rows
  if (rb >= n_nodes) return;

  int start[8], cnt[8];
  int maxc = 0;
#pragma unroll
  for (int i = 0; i < 8; i++) {
    int r = rb + i;
    bool ok = r < n_nodes;
    start[i] = ok ? row_start[r] : 0;
    cnt[i] = ok ? count[r] : 0;
    maxc = max(maxc, cnt[i]);
  }

  float acc[8][8];
#pragma unroll
  for (int i = 0; i < 8; i++)
#pragma unroll
    for (int k = 0; k < 8; k++) acc[i][k] = 0.f;

  if (sub == 0) {  // self-loop terms
#pragma unroll
    for (int i = 0; i < 8; i++) {
      int r = rb + i;
      if (r < n_nodes) {
        short8 v = *(const short8*)(xwd + (size_t)r * OUT_SIZE + cg * 8);
#pragma unroll
        for (int k = 0; k < 8; k++) acc[i][k] = bf2f((unsigned short)v[k]);
      }
    }
  }

  for (int j = 0; j < maxc; j += 8) {
    int c[8];
    float m[8];
    int idx = j + sub;
#pragma unroll
    for (int i = 0; i < 8; i++) {
      bool act = idx < cnt[i];
      c[i] = act ? (int)colsp[start[i] + idx] : rb;  // dummy -> hot line
      m[i] = act ? 1.0f : 0.0f;
    }
    short8 v[8];
#pragma unroll
    for (int i = 0; i < 8; i++)
      v[i] = *(const short8*)(xwd + (size_t)c[i] * OUT_SIZE + cg * 8);
#pragma unroll
    for (int i = 0; i < 8; i++)
#pragma unroll
      for (int k = 0; k < 8; k++)
        acc[i][k] += m[i] * bf2f((unsigned short)v[i][k]);
  }

#pragma unroll
  for (int i = 0; i < 8; i++)
#pragma unroll
    for (int k = 0; k < 8; k++) {
      acc[i][k] += __shfl_xor(acc[i][k], 1);
      acc[i][k] += __shfl_xor(acc[i][k], 2);
      acc[i][k] += __shfl_xor(acc[i][k], 4);
    }

  if (sub == 0) {
#pragma unroll
    for (int i = 0; i < 8; i++) {
      int r = rb + i;
      if (r < n_nodes) {
        float dr = dinv[r];
        float* dst = out + (size_t)r * OUT_SIZE + cg * 8;
        *(float4*)(dst) =
            make_float4(dr * acc[i][0], dr * acc[i][1], dr * acc[i][2],
                        dr * acc[i][3]);
        *(float4*)(dst + 4) =
            make_float4(dr * acc[i][4], dr * acc[i][5], dr * acc[i][6],
                        dr * acc[i][7]);
      }
    }
  }
}

// ---------------------------------------------------------------------------
extern "C" void kernel_launch(void* const* d_in, const int* in_sizes, int n_in,
                              void* d_out, int out_size, void* d_ws,
                              size_t ws_size, hipStream_t stream) {
  const int* edge_index = (const int*)d_in[0];
  const float* x = (const float*)d_in[1];
  const float* W = (const float*)d_in[3];

  int n_edges = in_sizes[0] / 2;
  int n_nodes = in_sizes[1] / IN_SIZE;
  const int* row = edge_index;
  const int* col = edge_index + n_edges;
  float* out = (float*)d_out;

  int nbuck = (n_nodes + BROWS - 1) >> BSHIFT;  // 782

  // Workspace: count[N] | row_start[N] | dinv[N] | coarse_cursor(4KB) |
  //            pairs[nbuck*CAP u32] | colsp[nbuck*CAP u32] |
  //            xwd[N*64 bf16] | Wb[64*256 bf16]
  char* ws = (char*)d_ws;
  size_t nb = ((size_t)n_nodes * 4 + 15) & ~(size_t)15;
  int* count = (int*)ws;
  int* row_start = (int*)(ws + nb);
  float* dinv = (float*)(ws + 2 * nb);
  int* coarse_cursor = (int*)(ws + 3 * nb);
  size_t bucketsB = (size_t)nbuck * CAP * 4;  // 8,007,680 B
  unsigned* pairs = (unsigned*)(ws + 3 * nb + 4096);
  unsigned* colsp = (unsigned*)(ws + 3 * nb + 4096 + bucketsB);
  unsigned short* xwd =
      (unsigned short*)(ws + 3 * nb + 4096 + 2 * bucketsB);
  unsigned short* Wb =
      (unsigned short*)(ws + 3 * nb + 4096 + 2 * bucketsB +
                        (size_t)n_nodes * OUT_SIZE * 2);

  wconv_kernel<<<(OUT_SIZE * IN_SIZE + 255) / 256, 256, 0, stream>>>(
      W, Wb, coarse_cursor, OUT_SIZE * IN_SIZE, nbuck);
  int nb1 = (n_edges + K1_TILE - 1) / K1_TILE;
  bucket_coarse_kernel<<<nb1, 256, 0, stream>>>(row, col, coarse_cursor,
                                                pairs, n_edges, nbuck);
  bucket_fine_kernel<<<nbuck, 256, 0, stream>>>(coarse_cursor, pairs, colsp,
                                                count, row_start, dinv,
                                                n_nodes);
  matmul_kernel<<<(n_nodes + 127) / 128, 512, 0, stream>>>(x, Wb, dinv, xwd,
                                                           n_nodes);
  gather_kernel<<<(n_nodes + 31) / 32, 256, 0, stream>>>(
      row_start, count, colsp, dinv, xwd, out, n_nodes);
}

// Round 10
// 267.191 us; speedup vs baseline: 1.0487x; 1.0487x over previous
//
#include <hip/hip_runtime.h>

#define IN_SIZE 256
#define OUT_SIZE 64
#define BSHIFT 7         // 128-row buckets
#define BROWS 128
#define BMASK 127
#define CAP 2560         // bucket capacity: mean 2046, sigma 45 -> +11 sigma
#define K1_TILE 4096     // edges per K1 block (16 per thread)

typedef __attribute__((ext_vector_type(8))) short short8;   // 8 bf16, 4 VGPRs
typedef __attribute__((ext_vector_type(4))) float floatx4;  // MFMA acc

__device__ inline unsigned short f2bf(float f) {
  unsigned u = __builtin_bit_cast(unsigned, f);
  u += 0x7fff + ((u >> 16) & 1);  // round-to-nearest-even
  return (unsigned short)(u >> 16);
}
__device__ inline float bf2f(unsigned short u) {
  unsigned v = (unsigned)u << 16;
  return __builtin_bit_cast(float, v);
}

// ---------------------------------------------------------------------------
// Stage 0: W fp32 -> bf16 once + zero the coarse cursors (fused memset).
__global__ __launch_bounds__(256) void wconv_kernel(const float* __restrict__ W,
                                                    unsigned short* __restrict__ Wb,
                                                    int* __restrict__ coarse_cursor,
                                                    int total, int nbuck) {
  int i = blockIdx.x * 256 + threadIdx.x;
  if (i < total) Wb[i] = f2bf(W[i]);
  if (i < nbuck) coarse_cursor[i] = 0;
}

// ---------------------------------------------------------------------------
// K1: coarse bucketing by row>>7 into 782 padded regions.
__global__ __launch_bounds__(256) void bucket_coarse_kernel(
    const int* __restrict__ row, const int* __restrict__ col,
    int* __restrict__ coarse_cursor, unsigned* __restrict__ pairs,
    int n_edges, int nbuck) {
  __shared__ int hist[1024];   // >= nbuck (782)
  int tid = threadIdx.x;
#pragma unroll
  for (int i = 0; i < 4; i++) hist[tid + i * 256] = 0;
  __syncthreads();

  int r[16], c[16];
  int ebase = blockIdx.x * K1_TILE + tid;
#pragma unroll
  for (int i = 0; i < 16; i++) {
    int e = ebase + i * 256;
    bool ok = e < n_edges;
    r[i] = ok ? row[e] : -1;
    c[i] = ok ? col[e] : -1;
    if (ok && r[i] != c[i]) atomicAdd(&hist[r[i] >> BSHIFT], 1);
  }
  __syncthreads();

  for (int i = tid; i < nbuck; i += 256) {
    int cnt = hist[i];
    if (cnt) hist[i] = atomicAdd(&coarse_cursor[i], cnt);
  }
  __syncthreads();

#pragma unroll
  for (int i = 0; i < 16; i++) {
    if (r[i] >= 0 && r[i] != c[i]) {
      int bin = r[i] >> BSHIFT;
      int slot = atomicAdd(&hist[bin], 1);  // LDS cursor
      if (slot < CAP)
        pairs[(size_t)bin * CAP + slot] =
            ((unsigned)(r[i] & BMASK) << 17) | (unsigned)c[i];
    }
  }
}

// ---------------------------------------------------------------------------
// K2: fine CSR build, single-pass (pairs copied to LDS while histogramming).
__global__ __launch_bounds__(256) void bucket_fine_kernel(
    const int* __restrict__ coarse_cursor, const unsigned* __restrict__ pairs,
    unsigned* __restrict__ colsp, int* __restrict__ count,
    int* __restrict__ row_start, float* __restrict__ dinv, int n_nodes) {
  __shared__ unsigned lpair[CAP];  // 10 KB
  __shared__ int hist[BROWS];
  __shared__ int scn[BROWS];
  int tid = threadIdx.x;
  int b = blockIdx.x;
  size_t base = (size_t)b * CAP;
  int n_b = coarse_cursor[b];
  if (n_b > CAP) n_b = CAP;

  if (tid < BROWS) hist[tid] = 0;
  __syncthreads();

  for (int i = tid; i < n_b; i += 256) {  // copy + histogram in one pass
    unsigned p = pairs[base + i];
    lpair[i] = p;
    atomicAdd(&hist[p >> 17], 1);
  }
  __syncthreads();

  if (tid < BROWS) scn[tid] = hist[tid];
  __syncthreads();
  for (int off = 1; off < BROWS; off <<= 1) {
    int t = (tid >= off && tid < BROWS) ? scn[tid - off] : 0;
    __syncthreads();
    if (tid < BROWS) scn[tid] += t;
    __syncthreads();
  }

  if (tid < BROWS) {
    int e = (tid > 0) ? scn[tid - 1] : 0;
    int r = b * BROWS + tid;
    if (r < n_nodes) {
      int deg = hist[tid];
      count[r] = deg;
      row_start[r] = (int)base + e;
      dinv[r] = rsqrtf((float)deg + 1.0f);
    }
    hist[tid] = e;  // becomes scatter cursor
  }
  __syncthreads();

  for (int i = tid; i < n_b; i += 256) {
    unsigned p = lpair[i];
    int slot = atomicAdd(&hist[p >> 17], 1);
    colsp[base + slot] = p & 0x1FFFFu;
  }
}

// ---------------------------------------------------------------------------
// Stage 4: xwd = dinv * (x @ W.T), output bf16 [N][64]. 512 threads = 8 waves
// = 128 nodes per block; W staged to LDS once per 128 nodes. Direct
// global->reg x loads; no barriers in the k-loop.
#define WPAD 264  // 256+8 shorts
__global__ __launch_bounds__(512) void matmul_kernel(
    const float* __restrict__ x, const unsigned short* __restrict__ Wb,
    const float* __restrict__ dinv, unsigned short* __restrict__ xwd,
    int n_nodes) {
  __shared__ unsigned short w_lds[64][WPAD];

  int tid = threadIdx.x;
  int wave = tid >> 6;    // 0..7
  int lane = tid & 63;
  int quad = lane >> 4;   // 0..3
  int lcol = lane & 15;   // 0..15
  long nbase = (long)blockIdx.x * 128;

  {  // stage W: 512 threads, each 32 shorts (4 x short8)
    int r = tid >> 3;     // 0..63
    int q = tid & 7;      // 8 chunks of 32 shorts
    const unsigned short* src = Wb + (size_t)r * IN_SIZE + q * 32;
#pragma unroll
    for (int i = 0; i < 4; i++)
      *(short8*)(&w_lds[r][q * 32 + i * 8]) = *(const short8*)(src + i * 8);
  }
  __syncthreads();

  long node = nbase + wave * 16 + lcol;
  long nclamp = (node < (long)n_nodes) ? node : (long)(n_nodes - 1);
  const float* xrow = x + nclamp * IN_SIZE;

  floatx4 acc[4];
#pragma unroll
  for (int t = 0; t < 4; t++) acc[t] = (floatx4){0.f, 0.f, 0.f, 0.f};

#pragma unroll
  for (int kk = 0; kk < 8; kk++) {
    const float* p = xrow + kk * 32 + quad * 8;
    float4 a = *(const float4*)(p);
    float4 bb = *(const float4*)(p + 4);
    short8 bfrag;
    bfrag[0] = (short)f2bf(a.x);  bfrag[1] = (short)f2bf(a.y);
    bfrag[2] = (short)f2bf(a.z);  bfrag[3] = (short)f2bf(a.w);
    bfrag[4] = (short)f2bf(bb.x); bfrag[5] = (short)f2bf(bb.y);
    bfrag[6] = (short)f2bf(bb.z); bfrag[7] = (short)f2bf(bb.w);
#pragma unroll
    for (int t = 0; t < 4; t++) {
      short8 afrag = *(const short8*)(&w_lds[t * 16 + lcol][kk * 32 + quad * 8]);
      acc[t] =
          __builtin_amdgcn_mfma_f32_16x16x32_bf16(afrag, bfrag, acc[t], 0, 0, 0);
    }
  }

  if (node < (long)n_nodes) {
    float dv = dinv[node];
#pragma unroll
    for (int t = 0; t < 4; t++) {
      ushort4 sv;
      sv.x = f2bf(dv * acc[t][0]);
      sv.y = f2bf(dv * acc[t][1]);
      sv.z = f2bf(dv * acc[t][2]);
      sv.w = f2bf(dv * acc[t][3]);
      *(ushort4*)(xwd + node * OUT_SIZE + t * 16 + quad * 4) = sv;
    }
  }
}

// ---------------------------------------------------------------------------
// Stage 5: CSR gather, 4 rows per wave (16 per block) — the round-7 config:
// acc[4][8] = 32 VGPRs keeps the kernel under the 64-reg occupancy step
// (8-row variant hit 80 VGPR -> 26% occupancy -> regression).
__global__ __launch_bounds__(256) void gather_kernel(
    const int* __restrict__ row_start, const int* __restrict__ count,
    const unsigned* __restrict__ colsp, const float* __restrict__ dinv,
    const unsigned short* __restrict__ xwd, float* __restrict__ out,
    int n_nodes) {
  int lane = threadIdx.x & 63;
  int wave = threadIdx.x >> 6;
  int sub = lane & 7;   // edge slot
  int cg = lane >> 3;   // channels cg*8 .. cg*8+7
  int rb = (blockIdx.x * 4 + wave) * 4;  // first of 4 rows
  if (rb >= n_nodes) return;

  int start[4], cnt[4];
  int maxc = 0;
#pragma unroll
  for (int i = 0; i < 4; i++) {
    int r = rb + i;
    bool ok = r < n_nodes;
    start[i] = ok ? row_start[r] : 0;
    cnt[i] = ok ? count[r] : 0;
    maxc = max(maxc, cnt[i]);
  }

  float acc[4][8];
#pragma unroll
  for (int i = 0; i < 4; i++)
#pragma unroll
    for (int k = 0; k < 8; k++) acc[i][k] = 0.f;

  if (sub == 0) {  // self-loop terms
#pragma unroll
    for (int i = 0; i < 4; i++) {
      int r = rb + i;
      if (r < n_nodes) {
        short8 v = *(const short8*)(xwd + (size_t)r * OUT_SIZE + cg * 8);
#pragma unroll
        for (int k = 0; k < 8; k++) acc[i][k] = bf2f((unsigned short)v[k]);
      }
    }
  }

  for (int j = 0; j < maxc; j += 8) {
    int c[4];
    float m[4];
    int idx = j + sub;
#pragma unroll
    for (int i = 0; i < 4; i++) {
      bool act = idx < cnt[i];
      c[i] = act ? (int)colsp[start[i] + idx] : rb;  // dummy -> hot line
      m[i] = act ? 1.0f : 0.0f;
    }
    short8 v[4];
#pragma unroll
    for (int i = 0; i < 4; i++)
      v[i] = *(const short8*)(xwd + (size_t)c[i] * OUT_SIZE + cg * 8);
#pragma unroll
    for (int i = 0; i < 4; i++)
#pragma unroll
      for (int k = 0; k < 8; k++)
        acc[i][k] += m[i] * bf2f((unsigned short)v[i][k]);
  }

#pragma unroll
  for (int i = 0; i < 4; i++)
#pragma unroll
    for (int k = 0; k < 8; k++) {
      acc[i][k] += __shfl_xor(acc[i][k], 1);
      acc[i][k] += __shfl_xor(acc[i][k], 2);
      acc[i][k] += __shfl_xor(acc[i][k], 4);
    }

  if (sub == 0) {
#pragma unroll
    for (int i = 0; i < 4; i++) {
      int r = rb + i;
      if (r < n_nodes) {
        float dr = dinv[r];
        float* dst = out + (size_t)r * OUT_SIZE + cg * 8;
        *(float4*)(dst) =
            make_float4(dr * acc[i][0], dr * acc[i][1], dr * acc[i][2],
                        dr * acc[i][3]);
        *(float4*)(dst + 4) =
            make_float4(dr * acc[i][4], dr * acc[i][5], dr * acc[i][6],
                        dr * acc[i][7]);
      }
    }
  }
}

// ---------------------------------------------------------------------------
extern "C" void kernel_launch(void* const* d_in, const int* in_sizes, int n_in,
                              void* d_out, int out_size, void* d_ws,
                              size_t ws_size, hipStream_t stream) {
  const int* edge_index = (const int*)d_in[0];
  const float* x = (const float*)d_in[1];
  const float* W = (const float*)d_in[3];

  int n_edges = in_sizes[0] / 2;
  int n_nodes = in_sizes[1] / IN_SIZE;
  const int* row = edge_index;
  const int* col = edge_index + n_edges;
  float* out = (float*)d_out;

  int nbuck = (n_nodes + BROWS - 1) >> BSHIFT;  // 782

  // Workspace: count[N] | row_start[N] | dinv[N] | coarse_cursor(4KB) |
  //            pairs[nbuck*CAP u32] | colsp[nbuck*CAP u32] |
  //            xwd[N*64 bf16] | Wb[64*256 bf16]
  char* ws = (char*)d_ws;
  size_t nb = ((size_t)n_nodes * 4 + 15) & ~(size_t)15;
  int* count = (int*)ws;
  int* row_start = (int*)(ws + nb);
  float* dinv = (float*)(ws + 2 * nb);
  int* coarse_cursor = (int*)(ws + 3 * nb);
  size_t bucketsB = (size_t)nbuck * CAP * 4;  // 8,007,680 B
  unsigned* pairs = (unsigned*)(ws + 3 * nb + 4096);
  unsigned* colsp = (unsigned*)(ws + 3 * nb + 4096 + bucketsB);
  unsigned short* xwd =
      (unsigned short*)(ws + 3 * nb + 4096 + 2 * bucketsB);
  unsigned short* Wb =
      (unsigned short*)(ws + 3 * nb + 4096 + 2 * bucketsB +
                        (size_t)n_nodes * OUT_SIZE * 2);

  wconv_kernel<<<(OUT_SIZE * IN_SIZE + 255) / 256, 256, 0, stream>>>(
      W, Wb, coarse_cursor, OUT_SIZE * IN_SIZE, nbuck);
  int nb1 = (n_edges + K1_TILE - 1) / K1_TILE;
  bucket_coarse_kernel<<<nb1, 256, 0, stream>>>(row, col, coarse_cursor,
                                                pairs, n_edges, nbuck);
  bucket_fine_kernel<<<nbuck, 256, 0, stream>>>(coarse_cursor, pairs, colsp,
                                                count, row_start, dinv,
                                                n_nodes);
  matmul_kernel<<<(n_nodes + 127) / 128, 512, 0, stream>>>(x, Wb, dinv, xwd,
                                                           n_nodes);
  gather_kernel<<<(n_nodes + 15) / 16, 256, 0, stream>>>(
      row_start, count, colsp, dinv, xwd, out, n_nodes);
}